// Round 3
// baseline (371.079 us; speedup 1.0000x reference)
//
#include <hip/hip_runtime.h>
#include <hip/hip_bf16.h>

#define N_NODES 100000
#define N_EDGES 1600000
#define IN_F 128
#define C1 64      // HEADS*HID
#define NC 16      // classes / layer2 width

#define SCAN_TILE 1024
#define SCAN_NB ((N_NODES + SCAN_TILE - 1) / SCAN_TILE)   // 98 blocks
#define GEMM1_NB (N_NODES / 16)                           // 6250; 6250*256 == N_EDGES
#define HIST_NB ((N_EDGES + 1023) / 1024)                 // 1563 (scatter grid)

__device__ __forceinline__ float lrelu(float x) { return fmaxf(x, 0.2f * x); }
__device__ __forceinline__ float selh(float4 v, int h) {
    return (h == 0) ? v.x : (h == 1) ? v.y : (h == 2) ? v.z : v.w;
}

// ---------------- fused: histogram+rank interleaved INTO layer1 GEMM ---------
// Every block does a 16-node GEMM + 256 edges of histogram (1 edge/thread;
// 6250*256 == N_EDGES). The atomic is issued first; its result store sinks
// below the LDS staging issue. Inner loop kept at the 40-VGPR form (scalar x
// read, unroll 4): float4-x full-unroll pipelined ~20 b128 reads -> 168 VGPR
// -> 11% occupancy -> regression (round 1 lesson).
__global__ __launch_bounds__(256) void k_hist_gemm1(
    const int* __restrict__ e_dst, int* __restrict__ deg, int* __restrict__ rank,
    const float* __restrict__ x, const float* __restrict__ W1,
    const float* __restrict__ att_src1, const float* __restrict__ att_dst1,
    float* __restrict__ h1, float* __restrict__ a_src1, float* __restrict__ a_dst1) {
    __shared__ __align__(16) float wS[64 * C1];     // 16 KB, one k-half of W1
    __shared__ __align__(16) float xS[16 * 132];    // stride 132: aligned + conflict-free
    __shared__ float aSs[C1], aSd[C1];
    int tid = threadIdx.x;

    // ---- hist: one edge per thread
    int e = blockIdx.x * 256 + tid;
    int d = e_dst[e];
    int rk = atomicAdd(&deg[d], 1);                 // issue early; wait later

    // ---- stage x tile while the atomic is in flight
    int node0 = blockIdx.x * 16;
    for (int i = tid; i < (16 * IN_F) / 4; i += 256) {
        int r = i >> 5, c4 = (i & 31) << 2;          // 32 float4 per 128-wide row
        *(float4*)&xS[r * 132 + c4] = *(const float4*)&x[(node0 + r) * IN_F + c4];
    }
    if (tid < C1) { aSs[tid] = att_src1[tid]; aSd[tid] = att_dst1[tid]; }
    rank[e] = rk;                                   // vmcnt wait lands here, after staging issue

    // ---- gemm1: 16 nodes/block; thread t: node_l=t>>4, cols (t&15)*4..+3
    int node_l = tid >> 4;
    int cq = (tid & 15) << 2;
    const float* xrow = &xS[node_l * 132];
    float4 acc = {0.f, 0.f, 0.f, 0.f};
#pragma unroll
    for (int kt = 0; kt < 2; kt++) {                // two 64-wide k-tiles of W1
        __syncthreads();                            // protect wS reuse
        for (int i = tid; i < (64 * C1) / 4; i += 256)
            *(float4*)&wS[i * 4] = *(const float4*)&W1[kt * 64 * C1 + i * 4];
        __syncthreads();
        const float* xk = xrow + kt * 64;
#pragma unroll 4
        for (int k = 0; k < 64; k++) {
            float xv = xk[k];
            float4 wv = *(const float4*)&wS[k * C1 + cq];
            acc.x += xv * wv.x; acc.y += xv * wv.y; acc.z += xv * wv.z; acc.w += xv * wv.w;
        }
    }
    int node = node0 + node_l;
    *(float4*)&h1[node * C1 + cq] = acc;

    float ps = acc.x * aSs[cq] + acc.y * aSs[cq + 1] + acc.z * aSs[cq + 2] + acc.w * aSs[cq + 3];
    float pd = acc.x * aSd[cq] + acc.y * aSd[cq + 1] + acc.z * aSd[cq + 2] + acc.w * aSd[cq + 3];
    ps += __shfl_xor(ps, 1); ps += __shfl_xor(ps, 2);
    pd += __shfl_xor(pd, 1); pd += __shfl_xor(pd, 2);
    if ((tid & 3) == 0) {
        int h = (tid & 15) >> 2;
        a_src1[node * 4 + h] = ps;
        a_dst1[node * 4 + h] = pd;
    }
}

// pass 1: per-block sums of deg (1024 elems per 256-thread block)
__global__ __launch_bounds__(256) void k_scan1(const int* __restrict__ deg,
                                               int* __restrict__ partial) {
    __shared__ int wsum[4];
    int tid = threadIdx.x;
    int i0 = blockIdx.x * SCAN_TILE + tid * 4;
    int s = 0;
#pragma unroll
    for (int j = 0; j < 4; j++) { int i = i0 + j; if (i < N_NODES) s += deg[i]; }
    for (int off = 32; off; off >>= 1) s += __shfl_xor(s, off);
    if ((tid & 63) == 0) wsum[tid >> 6] = s;
    __syncthreads();
    if (tid == 0) partial[blockIdx.x] = wsum[0] + wsum[1] + wsum[2] + wsum[3];
}

// pass 2: exclusive scan of the 98 partials (single tiny block)
__global__ void k_scan2(const int* __restrict__ partial, int* __restrict__ pscan,
                        int* __restrict__ rowptr) {
    __shared__ int buf[128];
    int tid = threadIdx.x;
    int v = (tid < SCAN_NB) ? partial[tid] : 0;
    buf[tid] = v;
    __syncthreads();
    for (int d = 1; d < 128; d <<= 1) {
        int t = (tid >= d) ? buf[tid - d] : 0;
        __syncthreads();
        buf[tid] += t;
        __syncthreads();
    }
    if (tid < SCAN_NB) pscan[tid] = buf[tid] - v;    // exclusive
    if (tid == 0) rowptr[N_NODES] = N_EDGES;         // total is static
}

// pass 3: block-local exclusive scan + block offset -> rowptr
__global__ __launch_bounds__(256) void k_scan3(const int* __restrict__ deg,
                                               const int* __restrict__ pscan,
                                               int* __restrict__ rowptr) {
    __shared__ int wsum[4];
    int tid = threadIdx.x, lane = tid & 63, wave = tid >> 6;
    int i0 = blockIdx.x * SCAN_TILE + tid * 4;
    int v0 = 0, v1 = 0, v2 = 0, v3 = 0;
    if (i0 + 0 < N_NODES) v0 = deg[i0 + 0];
    if (i0 + 1 < N_NODES) v1 = deg[i0 + 1];
    if (i0 + 2 < N_NODES) v2 = deg[i0 + 2];
    if (i0 + 3 < N_NODES) v3 = deg[i0 + 3];
    int s0 = v0, s1 = s0 + v1, s2 = s1 + v2, s3 = s2 + v3;   // thread-local inclusive
    int t = s3;                                              // wave inclusive scan
    for (int off = 1; off < 64; off <<= 1) {
        int u = __shfl_up(t, off);
        if (lane >= off) t += u;
    }
    if (lane == 63) wsum[wave] = t;
    __syncthreads();
    int woff = 0;
    for (int w = 0; w < wave; w++) woff += wsum[w];
    int base = pscan[blockIdx.x] + woff + (t - s3);          // exclusive prefix
    if (i0 + 0 < N_NODES) rowptr[i0 + 0] = base;
    if (i0 + 1 < N_NODES) rowptr[i0 + 1] = base + s0;
    if (i0 + 2 < N_NODES) rowptr[i0 + 2] = base + s1;
    if (i0 + 3 < N_NODES) rowptr[i0 + 3] = base + s2;
}

// atomic-free scatter: rank was captured during hist
__global__ __launch_bounds__(256) void k_scatter(
    const int* __restrict__ e_src, const int* __restrict__ e_dst,
    const int* __restrict__ rank, const int* __restrict__ rowptr,
    int* __restrict__ csr_src) {
    int e0 = blockIdx.x * 1024 + threadIdx.x;
#pragma unroll
    for (int j = 0; j < 4; j++) {
        int e = e0 + j * 256;
        if (e < N_EDGES)
            csr_src[rowptr[e_dst[e]] + rank[e]] = e_src[e];
    }
}

// ---------------- layer 1 segment-softmax + aggregate (one wave per node) ----
// Gather restructured: quarter-wave per edge, float4 per lane. Per 4 edges:
// 1 global_load_dwordx4 + 2 scalar ds_reads + 4 FMA (was 2x ds_read_b128 +
// 4 dword loads + 4 addr chains). Same bytes, ~2x fewer issue slots, 4x fewer
// VMEM instrs. src stored pre-scaled (<<8 = row byte offset) so the address
// is one v_add off a 32-bit voffset. LDS stride 72 for per-head weights ->
// 16-distinct-bank reads, 2-way writes (free) -> kills the 3.2M conflicts.
// + FUSED layer-2 GEMM/attention-dot epilogue (as round 2).
__global__ __launch_bounds__(256) void k_agg1(
    const float* __restrict__ h1, const float* __restrict__ a_src1,
    const float* __restrict__ a_dst1, const int* __restrict__ rowptr,
    const int* __restrict__ csr_src, const float* __restrict__ b1,
    const float* __restrict__ W2, const float* __restrict__ att_src2,
    const float* __restrict__ att_dst2,
    float* __restrict__ out_emb, float* __restrict__ h2,
    float* __restrict__ a_src2, float* __restrict__ a_dst2) {
    __shared__ int   srcS[4][68];                  // [wave][edge] = src*256 (byte off)
    __shared__ float wW[4][4][72];                 // [wave][head][edge]; stride 72 -> banks 8h+e
    __shared__ __align__(16) float w2S[C1 * NC];   // 4 KB [k][c]
    __shared__ float oS[4][C1];                    // per-wave embedding row
    __shared__ float aS2[NC], aD2[NC];
    int tid = threadIdx.x;
    int lane = tid & 63, wave = tid >> 6;
    int node = blockIdx.x * 4 + wave;
    int q = lane >> 4;                              // quarter: which edge of 4
    int c4 = (lane & 15) << 2;                      // 4 owned output cols
    int hh = (lane & 15) >> 2;                      // head of owned cols
    const char* h1b = (const char*)h1;

    if (tid < (C1 * NC) / 4)
        *(float4*)&w2S[tid * 4] = *(const float4*)&W2[tid * 4];
    if (tid < NC) { aS2[tid] = att_src2[tid]; aD2[tid] = att_dst2[tid]; }

    int rs = rowptr[node];
    int deg = rowptr[node + 1] - rs;

    float4 ad4 = *(const float4*)&a_dst1[node * 4];
    float4 as4 = *(const float4*)&a_src1[node * 4];
    float4 w04 = {__expf(lrelu(as4.x + ad4.x)), __expf(lrelu(as4.y + ad4.y)),
                  __expf(lrelu(as4.z + ad4.z)), __expf(lrelu(as4.w + ad4.w))};
    float w0h = selh(w04, hh);                      // self-loop weight for my head

    // self contribution (quarter 0 only; loads are the same line for all quarters)
    float4 self4 = *(const float4*)(h1b + (unsigned)(node * 256 + c4 * 4));
    float ws = (q == 0) ? w0h : 0.f;
    float4 acc = {ws * self4.x, ws * self4.y, ws * self4.z, ws * self4.w};
    float4 sac4 = {0.f, 0.f, 0.f, 0.f};            // lane-parallel denominator

    for (int base = 0; base < deg; base += 64) {
        int idx = base + lane;
        int s_l = 0;
        float4 w4 = {0.f, 0.f, 0.f, 0.f};
        if (idx < deg) {                            // lane-parallel weight compute
            s_l = csr_src[rs + idx];
            float4 as = *(const float4*)&a_src1[s_l * 4];
            w4.x = __expf(lrelu(as.x + ad4.x));
            w4.y = __expf(lrelu(as.y + ad4.y));
            w4.z = __expf(lrelu(as.z + ad4.z));
            w4.w = __expf(lrelu(as.w + ad4.w));
        }
        sac4.x += w4.x; sac4.y += w4.y; sac4.z += w4.z; sac4.w += w4.w;
        srcS[wave][lane] = s_l << 8;                // byte offset of h1 row
        wW[wave][0][lane] = w4.x;
        wW[wave][1][lane] = w4.y;
        wW[wave][2][lane] = w4.z;
        wW[wave][3][lane] = w4.w;
        int nrem4 = (min(64, deg - base) + 3) & ~3; // pad slots carry w=0
#pragma unroll 2
        for (int j = 0; j < nrem4; j += 4) {        // quarter q handles edge j+q
            int soff = srcS[wave][j + q];
            float wv = wW[wave][hh][j + q];
            float4 hv = *(const float4*)(h1b + (unsigned)(soff + c4 * 4));
            acc.x = fmaf(wv, hv.x, acc.x);
            acc.y = fmaf(wv, hv.y, acc.y);
            acc.z = fmaf(wv, hv.z, acc.z);
            acc.w = fmaf(wv, hv.w, acc.w);
        }
    }
    // merge quarter-wave partials (quarters processed disjoint edges)
    acc.x += __shfl_xor(acc.x, 16); acc.x += __shfl_xor(acc.x, 32);
    acc.y += __shfl_xor(acc.y, 16); acc.y += __shfl_xor(acc.y, 32);
    acc.z += __shfl_xor(acc.z, 16); acc.z += __shfl_xor(acc.z, 32);
    acc.w += __shfl_xor(acc.w, 16); acc.w += __shfl_xor(acc.w, 32);
    for (int off = 32; off; off >>= 1) {            // reduce denominator (once)
        sac4.x += __shfl_xor(sac4.x, off);
        sac4.y += __shfl_xor(sac4.y, off);
        sac4.z += __shfl_xor(sac4.z, off);
        sac4.w += __shfl_xor(sac4.w, off);
    }
    float rins = 1.f / (selh(sac4, hh) + w0h);

    float4 bv = *(const float4*)&b1[c4];
    float4 o4 = {acc.x * rins + bv.x, acc.y * rins + bv.y,
                 acc.z * rins + bv.z, acc.w * rins + bv.w};
    o4.x = (o4.x > 0.f) ? o4.x : expm1f(o4.x);      // ELU
    o4.y = (o4.y > 0.f) ? o4.y : expm1f(o4.y);
    o4.z = (o4.z > 0.f) ? o4.z : expm1f(o4.z);
    o4.w = (o4.w > 0.f) ? o4.w : expm1f(o4.w);
    if (q == 0) {
        *(float4*)&out_emb[node * C1 + c4] = o4;    // fp32 embeddings == h_act
        *(float4*)&oS[wave][c4] = o4;
    }

    // ---- fused layer-2 GEMM + attention dots (was k_gemm2) ----
    __syncthreads();                                // w2S/aS2 staged; oS visible
    int esub = lane >> 4, c = lane & 15;            // k-split: 4 groups x 16 k each
    float g = 0.f;
#pragma unroll
    for (int kk = 0; kk < 16; kk++) {
        int k = esub * 16 + kk;
        g = fmaf(oS[wave][k], w2S[k * NC + c], g);
    }
    g += __shfl_xor(g, 16); g += __shfl_xor(g, 32); // reduce across k-groups
    float ps = g * aS2[c], pd = g * aD2[c];
    for (int off = 8; off; off >>= 1) { ps += __shfl_xor(ps, off); pd += __shfl_xor(pd, off); }
    if (lane < NC) h2[node * NC + c] = g;
    if (lane == 0) { a_src2[node] = ps; a_dst2[node] = pd; }
}

// ---------------- layer 2 softmax-aggregate + log_softmax (no max pass) -----
__global__ __launch_bounds__(256) void k_agg2(
    const float* __restrict__ h2, const float* __restrict__ a_src2,
    const float* __restrict__ a_dst2, const int* __restrict__ rowptr,
    const int* __restrict__ csr_src, const float* __restrict__ b2,
    float* __restrict__ out_lsm) {
    __shared__ int2 swS[4][64];                     // [wave][edge] = (src, w)
    int tid = threadIdx.x;
    int lane = tid & 63, wave = tid >> 6;
    int node = blockIdx.x * 4 + wave;
    int esub = lane >> 4, c = lane & 15;
    int rs = rowptr[node];
    int deg = rowptr[node + 1] - rs;

    float adst = a_dst2[node];
    float w0 = __expf(lrelu(a_src2[node] + adst));
    float sacc_l = 0.f;                             // lane-parallel denominator
    float accA = (esub == 0) ? w0 * h2[node * NC + c] : 0.f;
    float accB = 0.f;

    for (int base = 0; base < deg; base += 64) {
        int idx = base + lane;
        int s_l = 0; float w_l = 0.f;
        if (idx < deg) {                            // lane-parallel weight compute
            s_l = csr_src[rs + idx];
            w_l = __expf(lrelu(a_src2[s_l] + adst));
        }
        sacc_l += w_l;
        swS[wave][lane] = make_int2(s_l, __float_as_int(w_l));
        int nrem8 = (min(64, deg - base) + 7) & ~7; // pad slots carry w=0
        for (int j2 = 0; j2 < nrem8; j2 += 8) {     // 2 pairs x (4 edges x 16 cols)
            int2 p0 = swS[wave][j2 + esub];
            int2 p1 = swS[wave][j2 + 4 + esub];
            accA = fmaf(__int_as_float(p0.y), h2[p0.x * NC + c], accA);
            accB = fmaf(__int_as_float(p1.y), h2[p1.x * NC + c], accB);
        }
    }
    float acc = accA + accB;
    acc += __shfl_xor(acc, 16); acc += __shfl_xor(acc, 32);
    for (int off = 32; off; off >>= 1) sacc_l += __shfl_xor(sacc_l, off);
    float sacc = sacc_l + w0;

    float logit = acc / sacc + b2[c];
    float mxl = logit;
    for (int off = 8; off; off >>= 1) mxl = fmaxf(mxl, __shfl_xor(mxl, off));
    float ex = __expf(logit - mxl);
    float se = ex;
    for (int off = 8; off; off >>= 1) se += __shfl_xor(se, off);
    float lsm = (logit - mxl) - __logf(se);
    if (esub == 0) out_lsm[node * NC + c] = lsm;
}

extern "C" void kernel_launch(void* const* d_in, const int* in_sizes, int n_in,
                              void* d_out, int out_size, void* d_ws, size_t ws_size,
                              hipStream_t stream) {
    const float* x   = (const float*)d_in[0];
    const int* ei    = (const int*)d_in[1];   // [2,E]: src row then dst row
    const float* W1  = (const float*)d_in[2];
    const float* as1 = (const float*)d_in[3];
    const float* ad1 = (const float*)d_in[4];
    const float* b1  = (const float*)d_in[5];
    const float* W2  = (const float*)d_in[6];
    const float* as2 = (const float*)d_in[7];
    const float* ad2 = (const float*)d_in[8];
    const float* b2  = (const float*)d_in[9];
    float* out = (float*)d_out;               // [N*16 log_softmax][N*64 embeddings]
    float* out_lsm = out;
    float* out_emb = out + (size_t)N_NODES * NC;

    float* ws = (float*)d_ws;
    float* h1     = ws;                              // N*64
    float* a_src1 = h1     + (size_t)N_NODES * C1;   // N*4
    float* a_dst1 = a_src1 + (size_t)N_NODES * 4;    // N*4
    float* h2     = a_dst1 + (size_t)N_NODES * 4;    // N*16
    float* a_src2 = h2     + (size_t)N_NODES * NC;   // N
    float* a_dst2 = a_src2 + (size_t)N_NODES;        // N
    int*   deg    = (int*)(a_dst2 + N_NODES);        // N
    int*   rowptr = deg + N_NODES;                   // N+1
    int*   csr    = rowptr + N_NODES + 1;            // E
    int*   rank   = csr + N_EDGES;                   // E
    int*   partial= rank + N_EDGES;                  // SCAN_NB
    int*   pscan  = partial + SCAN_NB;               // SCAN_NB

    const int* e_src = ei;
    const int* e_dst = ei + N_EDGES;

    hipMemsetAsync(deg, 0, (size_t)N_NODES * sizeof(int), stream);

    k_hist_gemm1<<<GEMM1_NB, 256, 0, stream>>>(
        e_dst, deg, rank, x, W1, as1, ad1, h1, a_src1, a_dst1);

    k_scan1<<<SCAN_NB, 256, 0, stream>>>(deg, partial);
    k_scan2<<<1, 128, 0, stream>>>(partial, pscan, rowptr);
    k_scan3<<<SCAN_NB, 256, 0, stream>>>(deg, pscan, rowptr);

    k_scatter<<<HIST_NB, 256, 0, stream>>>(e_src, e_dst, rank, rowptr, csr);

    k_agg1 <<<N_NODES / 4, 256, 0, stream>>>(h1, a_src1, a_dst1, rowptr, csr, b1,
                                             W2, as2, ad2, out_emb, h2, a_src2, a_dst2);
    k_agg2 <<<N_NODES / 4, 256, 0, stream>>>(h2, a_src2, a_dst2, rowptr, csr, b2, out_lsm);
}

// Round 4
// 356.458 us; speedup vs baseline: 1.0410x; 1.0410x over previous
//
#include <hip/hip_runtime.h>
#include <hip/hip_bf16.h>

#define N_NODES 100000
#define N_EDGES 1600000
#define IN_F 128
#define C1 64      // HEADS*HID
#define NC 16      // classes / layer2 width

#define SCAN_TILE 1024
#define SCAN_NB ((N_NODES + SCAN_TILE - 1) / SCAN_TILE)   // 98 blocks
#define GEMM1_NB (N_NODES / 16)                           // 6250; 6250*256 == N_EDGES
#define HIST_NB ((N_EDGES + 1023) / 1024)                 // 1563 (scatter grid)

__device__ __forceinline__ float lrelu(float x) { return fmaxf(x, 0.2f * x); }
__device__ __forceinline__ float selh(float4 v, int h) {
    return (h == 0) ? v.x : (h == 1) ? v.y : (h == 2) ? v.z : v.w;
}

// ---------------- fused: histogram+rank interleaved INTO layer1 GEMM ---------
// (unchanged from round 3 — dropped out of top-5 at <101us)
__global__ __launch_bounds__(256) void k_hist_gemm1(
    const int* __restrict__ e_dst, int* __restrict__ deg, int* __restrict__ rank,
    const float* __restrict__ x, const float* __restrict__ W1,
    const float* __restrict__ att_src1, const float* __restrict__ att_dst1,
    float* __restrict__ h1, float* __restrict__ a_src1, float* __restrict__ a_dst1) {
    __shared__ __align__(16) float wS[64 * C1];     // 16 KB, one k-half of W1
    __shared__ __align__(16) float xS[16 * 132];    // stride 132: aligned + conflict-free
    __shared__ float aSs[C1], aSd[C1];
    int tid = threadIdx.x;

    // ---- hist: one edge per thread
    int e = blockIdx.x * 256 + tid;
    int d = e_dst[e];
    int rk = atomicAdd(&deg[d], 1);                 // issue early; wait later

    // ---- stage x tile while the atomic is in flight
    int node0 = blockIdx.x * 16;
    for (int i = tid; i < (16 * IN_F) / 4; i += 256) {
        int r = i >> 5, c4 = (i & 31) << 2;          // 32 float4 per 128-wide row
        *(float4*)&xS[r * 132 + c4] = *(const float4*)&x[(node0 + r) * IN_F + c4];
    }
    if (tid < C1) { aSs[tid] = att_src1[tid]; aSd[tid] = att_dst1[tid]; }
    rank[e] = rk;                                   // vmcnt wait lands here, after staging issue

    // ---- gemm1: 16 nodes/block; thread t: node_l=t>>4, cols (t&15)*4..+3
    int node_l = tid >> 4;
    int cq = (tid & 15) << 2;
    const float* xrow = &xS[node_l * 132];
    float4 acc = {0.f, 0.f, 0.f, 0.f};
#pragma unroll
    for (int kt = 0; kt < 2; kt++) {                // two 64-wide k-tiles of W1
        __syncthreads();                            // protect wS reuse
        for (int i = tid; i < (64 * C1) / 4; i += 256)
            *(float4*)&wS[i * 4] = *(const float4*)&W1[kt * 64 * C1 + i * 4];
        __syncthreads();
        const float* xk = xrow + kt * 64;
#pragma unroll 4
        for (int k = 0; k < 64; k++) {
            float xv = xk[k];
            float4 wv = *(const float4*)&wS[k * C1 + cq];
            acc.x += xv * wv.x; acc.y += xv * wv.y; acc.z += xv * wv.z; acc.w += xv * wv.w;
        }
    }
    int node = node0 + node_l;
    *(float4*)&h1[node * C1 + cq] = acc;

    float ps = acc.x * aSs[cq] + acc.y * aSs[cq + 1] + acc.z * aSs[cq + 2] + acc.w * aSs[cq + 3];
    float pd = acc.x * aSd[cq] + acc.y * aSd[cq + 1] + acc.z * aSd[cq + 2] + acc.w * aSd[cq + 3];
    ps += __shfl_xor(ps, 1); ps += __shfl_xor(ps, 2);
    pd += __shfl_xor(pd, 1); pd += __shfl_xor(pd, 2);
    if ((tid & 3) == 0) {
        int h = (tid & 15) >> 2;
        a_src1[node * 4 + h] = ps;
        a_dst1[node * 4 + h] = pd;
    }
}

// pass 1: per-block sums of deg (1024 elems per 256-thread block)
__global__ __launch_bounds__(256) void k_scan1(const int* __restrict__ deg,
                                               int* __restrict__ partial) {
    __shared__ int wsum[4];
    int tid = threadIdx.x;
    int i0 = blockIdx.x * SCAN_TILE + tid * 4;
    int s = 0;
#pragma unroll
    for (int j = 0; j < 4; j++) { int i = i0 + j; if (i < N_NODES) s += deg[i]; }
    for (int off = 32; off; off >>= 1) s += __shfl_xor(s, off);
    if ((tid & 63) == 0) wsum[tid >> 6] = s;
    __syncthreads();
    if (tid == 0) partial[blockIdx.x] = wsum[0] + wsum[1] + wsum[2] + wsum[3];
}

// pass 2: exclusive scan of the 98 partials (single tiny block)
__global__ void k_scan2(const int* __restrict__ partial, int* __restrict__ pscan,
                        int* __restrict__ rowptr) {
    __shared__ int buf[128];
    int tid = threadIdx.x;
    int v = (tid < SCAN_NB) ? partial[tid] : 0;
    buf[tid] = v;
    __syncthreads();
    for (int d = 1; d < 128; d <<= 1) {
        int t = (tid >= d) ? buf[tid - d] : 0;
        __syncthreads();
        buf[tid] += t;
        __syncthreads();
    }
    if (tid < SCAN_NB) pscan[tid] = buf[tid] - v;    // exclusive
    if (tid == 0) rowptr[N_NODES] = N_EDGES;         // total is static
}

// pass 3: block-local exclusive scan + block offset -> rowptr
__global__ __launch_bounds__(256) void k_scan3(const int* __restrict__ deg,
                                               const int* __restrict__ pscan,
                                               int* __restrict__ rowptr) {
    __shared__ int wsum[4];
    int tid = threadIdx.x, lane = tid & 63, wave = tid >> 6;
    int i0 = blockIdx.x * SCAN_TILE + tid * 4;
    int v0 = 0, v1 = 0, v2 = 0, v3 = 0;
    if (i0 + 0 < N_NODES) v0 = deg[i0 + 0];
    if (i0 + 1 < N_NODES) v1 = deg[i0 + 1];
    if (i0 + 2 < N_NODES) v2 = deg[i0 + 2];
    if (i0 + 3 < N_NODES) v3 = deg[i0 + 3];
    int s0 = v0, s1 = s0 + v1, s2 = s1 + v2, s3 = s2 + v3;   // thread-local inclusive
    int t = s3;                                              // wave inclusive scan
    for (int off = 1; off < 64; off <<= 1) {
        int u = __shfl_up(t, off);
        if (lane >= off) t += u;
    }
    if (lane == 63) wsum[wave] = t;
    __syncthreads();
    int woff = 0;
    for (int w = 0; w < wave; w++) woff += wsum[w];
    int base = pscan[blockIdx.x] + woff + (t - s3);          // exclusive prefix
    if (i0 + 0 < N_NODES) rowptr[i0 + 0] = base;
    if (i0 + 1 < N_NODES) rowptr[i0 + 1] = base + s0;
    if (i0 + 2 < N_NODES) rowptr[i0 + 2] = base + s1;
    if (i0 + 3 < N_NODES) rowptr[i0 + 3] = base + s2;
}

// atomic-free scatter: rank was captured during hist
__global__ __launch_bounds__(256) void k_scatter(
    const int* __restrict__ e_src, const int* __restrict__ e_dst,
    const int* __restrict__ rank, const int* __restrict__ rowptr,
    int* __restrict__ csr_src) {
    int e0 = blockIdx.x * 1024 + threadIdx.x;
#pragma unroll
    for (int j = 0; j < 4; j++) {
        int e = e0 + j * 256;
        if (e < N_EDGES)
            csr_src[rowptr[e_dst[e]] + rank[e]] = e_src[e];
    }
}

// ---------------- layer 1 segment-softmax + aggregate ------------------------
// RESTRUCTURED: 16-lane group per node (4 nodes/wave, 16/block). At mean deg=16
// the old wave-per-node shape spent ~200 fixed wave-instrs (prologue, 75%-idle
// weight phase, 64-lane reductions, L2-GEMM epilogue) per 16 edges. Now:
// weight phase all-lane-useful, reductions are 4 shfl steps within the group,
// epilogue/L2-GEMM amortize over 4 nodes/wave. Gather rate unchanged
// (1 dwordx4/lane = 4 edges/wave/step). LDS strides: srcS[16][17] (17 odd ->
// group bases hit distinct banks), wW[16][17][4] (read addr 4g+4e+hl: 16
// distinct banks/wave), w2S[k*16+gl] (16 banks x 4-lane broadcast).
__global__ __launch_bounds__(256) void k_agg1(
    const float* __restrict__ h1, const float* __restrict__ a_src1,
    const float* __restrict__ a_dst1, const int* __restrict__ rowptr,
    const int* __restrict__ csr_src, const float* __restrict__ b1,
    const float* __restrict__ W2, const float* __restrict__ att_src2,
    const float* __restrict__ att_dst2,
    float* __restrict__ out_emb, float* __restrict__ h2,
    float* __restrict__ a_src2, float* __restrict__ a_dst2) {
    __shared__ int   srcS[16][17];                 // [group][edge] = src row byte off
    __shared__ __align__(16) float wW[16][17][4];  // [group][edge][head]
    __shared__ __align__(16) float w2S[C1 * NC];   // 4 KB [k][c]
    __shared__ float aS2[NC], aD2[NC];
    int tid = threadIdx.x;
    int g  = tid >> 4;                              // group in block (0..15)
    int gl = tid & 15;                              // lane in group
    int hl = gl >> 2;                               // head of my 4 owned cols
    int node = blockIdx.x * 16 + g;
    const char* h1b = (const char*)h1;
    int laneoff = gl << 4;                          // byte offset of my cols in a row

    if (tid < (C1 * NC) / 4)
        *(float4*)&w2S[tid * 4] = *(const float4*)&W2[tid * 4];
    if (tid < NC) { aS2[tid] = att_src2[tid]; aD2[tid] = att_dst2[tid]; }

    int rs  = rowptr[node];
    int deg = rowptr[node + 1] - rs;

    float4 ad4 = *(const float4*)&a_dst1[node * 4];  // broadcast within group
    float w0h = __expf(lrelu(a_src1[node * 4 + hl] + selh(ad4, hl)));  // self weight, my head

    float4 self4 = *(const float4*)(h1b + (unsigned)(node * 256 + laneoff));
    float4 acc = {w0h * self4.x, w0h * self4.y, w0h * self4.z, w0h * self4.w};
    float4 sac4 = {0.f, 0.f, 0.f, 0.f};             // per-lane partial denominator

    for (int base = 0; base < deg; base += 16) {    // 16 edges per group-chunk
        int idx = base + gl;
        int s_l = 0;
        float4 w4 = {0.f, 0.f, 0.f, 0.f};
        if (idx < deg) {                            // lane-parallel weight compute
            s_l = csr_src[rs + idx];
            float4 as = *(const float4*)&a_src1[s_l * 4];
            w4.x = __expf(lrelu(as.x + ad4.x));
            w4.y = __expf(lrelu(as.y + ad4.y));
            w4.z = __expf(lrelu(as.z + ad4.z));
            w4.w = __expf(lrelu(as.w + ad4.w));
        }
        sac4.x += w4.x; sac4.y += w4.y; sac4.z += w4.z; sac4.w += w4.w;
        srcS[g][gl] = s_l << 8;                     // row byte offset
        *(float4*)&wW[g][gl][0] = w4;               // one b128 per lane
        int nrem = min(16, deg - base);
#pragma unroll 4
        for (int j = 0; j < nrem; j++) {            // 1 edge/group/step = 4 edges/wave
            int soff = srcS[g][j];
            float wv = wW[g][j][hl];
            float4 hv = *(const float4*)(h1b + (unsigned)(soff + laneoff));
            acc.x = fmaf(wv, hv.x, acc.x);
            acc.y = fmaf(wv, hv.y, acc.y);
            acc.z = fmaf(wv, hv.z, acc.z);
            acc.w = fmaf(wv, hv.w, acc.w);
        }
    }
    // group-local denominator reduce (xor of lane bits 0-3 stays in group)
#pragma unroll
    for (int off = 1; off <= 8; off <<= 1) {
        sac4.x += __shfl_xor(sac4.x, off);
        sac4.y += __shfl_xor(sac4.y, off);
        sac4.z += __shfl_xor(sac4.z, off);
        sac4.w += __shfl_xor(sac4.w, off);
    }
    float rins = 1.f / (selh(sac4, hl) + w0h);

    float4 bv = *(const float4*)&b1[gl << 2];
    float4 o4 = {acc.x * rins + bv.x, acc.y * rins + bv.y,
                 acc.z * rins + bv.z, acc.w * rins + bv.w};
    o4.x = (o4.x > 0.f) ? o4.x : expm1f(o4.x);      // ELU
    o4.y = (o4.y > 0.f) ? o4.y : expm1f(o4.y);
    o4.z = (o4.z > 0.f) ? o4.z : expm1f(o4.z);
    o4.w = (o4.w > 0.f) ? o4.w : expm1f(o4.w);
    *(float4*)&out_emb[node * C1 + (gl << 2)] = o4; // 16 lanes x 16B = full row

    // ---- fused layer-2 GEMM + attention dots (o4 stays in registers) ----
    __syncthreads();                                // w2S/aS2 staged by all threads
    int lane = tid & 63;
    int lbase = lane & 48;                          // my group's base lane in wave
    float gacc = 0.f;
#pragma unroll
    for (int m = 0; m < 16; m++) {                  // k = 4m..4m+3 lives in lane lbase+m
        float ox = __shfl(o4.x, lbase + m);
        float oy = __shfl(o4.y, lbase + m);
        float oz = __shfl(o4.z, lbase + m);
        float ow = __shfl(o4.w, lbase + m);
        gacc = fmaf(ox, w2S[(4 * m + 0) * NC + gl], gacc);
        gacc = fmaf(oy, w2S[(4 * m + 1) * NC + gl], gacc);
        gacc = fmaf(oz, w2S[(4 * m + 2) * NC + gl], gacc);
        gacc = fmaf(ow, w2S[(4 * m + 3) * NC + gl], gacc);
    }
    h2[node * NC + gl] = gacc;                      // tid-contiguous across block
    float ps = gacc * aS2[gl], pd = gacc * aD2[gl];
#pragma unroll
    for (int off = 1; off <= 8; off <<= 1) { ps += __shfl_xor(ps, off); pd += __shfl_xor(pd, off); }
    if (gl == 0) { a_src2[node] = ps; a_dst2[node] = pd; }
}

// ---------------- layer 2 softmax-aggregate + log_softmax (no max pass) -----
__global__ __launch_bounds__(256) void k_agg2(
    const float* __restrict__ h2, const float* __restrict__ a_src2,
    const float* __restrict__ a_dst2, const int* __restrict__ rowptr,
    const int* __restrict__ csr_src, const float* __restrict__ b2,
    float* __restrict__ out_lsm) {
    __shared__ int2 swS[4][64];                     // [wave][edge] = (src, w)
    int tid = threadIdx.x;
    int lane = tid & 63, wave = tid >> 6;
    int node = blockIdx.x * 4 + wave;
    int esub = lane >> 4, c = lane & 15;
    int rs = rowptr[node];
    int deg = rowptr[node + 1] - rs;

    float adst = a_dst2[node];
    float w0 = __expf(lrelu(a_src2[node] + adst));
    float sacc_l = 0.f;                             // lane-parallel denominator
    float accA = (esub == 0) ? w0 * h2[node * NC + c] : 0.f;
    float accB = 0.f;

    for (int base = 0; base < deg; base += 64) {
        int idx = base + lane;
        int s_l = 0; float w_l = 0.f;
        if (idx < deg) {                            // lane-parallel weight compute
            s_l = csr_src[rs + idx];
            w_l = __expf(lrelu(a_src2[s_l] + adst));
        }
        sacc_l += w_l;
        swS[wave][lane] = make_int2(s_l, __float_as_int(w_l));
        int nrem8 = (min(64, deg - base) + 7) & ~7; // pad slots carry w=0
        for (int j2 = 0; j2 < nrem8; j2 += 8) {     // 2 pairs x (4 edges x 16 cols)
            int2 p0 = swS[wave][j2 + esub];
            int2 p1 = swS[wave][j2 + 4 + esub];
            accA = fmaf(__int_as_float(p0.y), h2[p0.x * NC + c], accA);
            accB = fmaf(__int_as_float(p1.y), h2[p1.x * NC + c], accB);
        }
    }
    float acc = accA + accB;
    acc += __shfl_xor(acc, 16); acc += __shfl_xor(acc, 32);
    for (int off = 32; off; off >>= 1) sacc_l += __shfl_xor(sacc_l, off);
    float sacc = sacc_l + w0;

    float logit = acc / sacc + b2[c];
    float mxl = logit;
    for (int off = 8; off; off >>= 1) mxl = fmaxf(mxl, __shfl_xor(mxl, off));
    float ex = __expf(logit - mxl);
    float se = ex;
    for (int off = 8; off; off >>= 1) se += __shfl_xor(se, off);
    float lsm = (logit - mxl) - __logf(se);
    if (esub == 0) out_lsm[node * NC + c] = lsm;
}

extern "C" void kernel_launch(void* const* d_in, const int* in_sizes, int n_in,
                              void* d_out, int out_size, void* d_ws, size_t ws_size,
                              hipStream_t stream) {
    const float* x   = (const float*)d_in[0];
    const int* ei    = (const int*)d_in[1];   // [2,E]: src row then dst row
    const float* W1  = (const float*)d_in[2];
    const float* as1 = (const float*)d_in[3];
    const float* ad1 = (const float*)d_in[4];
    const float* b1  = (const float*)d_in[5];
    const float* W2  = (const float*)d_in[6];
    const float* as2 = (const float*)d_in[7];
    const float* ad2 = (const float*)d_in[8];
    const float* b2  = (const float*)d_in[9];
    float* out = (float*)d_out;               // [N*16 log_softmax][N*64 embeddings]
    float* out_lsm = out;
    float* out_emb = out + (size_t)N_NODES * NC;

    float* ws = (float*)d_ws;
    float* h1     = ws;                              // N*64
    float* a_src1 = h1     + (size_t)N_NODES * C1;   // N*4
    float* a_dst1 = a_src1 + (size_t)N_NODES * 4;    // N*4
    float* h2     = a_dst1 + (size_t)N_NODES * 4;    // N*16
    float* a_src2 = h2     + (size_t)N_NODES * NC;   // N
    float* a_dst2 = a_src2 + (size_t)N_NODES;        // N
    int*   deg    = (int*)(a_dst2 + N_NODES);        // N
    int*   rowptr = deg + N_NODES;                   // N+1
    int*   csr    = rowptr + N_NODES + 1;            // E
    int*   rank   = csr + N_EDGES;                   // E
    int*   partial= rank + N_EDGES;                  // SCAN_NB
    int*   pscan  = partial + SCAN_NB;               // SCAN_NB

    const int* e_src = ei;
    const int* e_dst = ei + N_EDGES;

    hipMemsetAsync(deg, 0, (size_t)N_NODES * sizeof(int), stream);

    k_hist_gemm1<<<GEMM1_NB, 256, 0, stream>>>(
        e_dst, deg, rank, x, W1, as1, ad1, h1, a_src1, a_dst1);

    k_scan1<<<SCAN_NB, 256, 0, stream>>>(deg, partial);
    k_scan2<<<1, 128, 0, stream>>>(partial, pscan, rowptr);
    k_scan3<<<SCAN_NB, 256, 0, stream>>>(deg, pscan, rowptr);

    k_scatter<<<HIST_NB, 256, 0, stream>>>(e_src, e_dst, rank, rowptr, csr);

    k_agg1 <<<N_NODES / 16, 256, 0, stream>>>(h1, a_src1, a_dst1, rowptr, csr, b1,
                                              W2, as2, ad2, out_emb, h2, a_src2, a_dst2);
    k_agg2 <<<N_NODES / 4, 256, 0, stream>>>(h2, a_src2, a_dst2, rowptr, csr, b2, out_lsm);
}